// Round 9
// baseline (3260.156 us; speedup 1.0000x reference)
//
// LSTMDecoder on MI355X — round 16: R15 resubmit (infra-failure suspected), cvt de-risked.
//
// Journal:
// * R2: multi-kernel PASSED 0.0117 @ 9763us. R3-R6: barrier/coop failed -> abandoned.
//   (R6 failed twice on container with no fault found; R7 resubmit ran fine. Precedent.)
// * R7 (6627) gemm8 vmcnt serialization. R8 (4615) reg prefetch. R9 (7230 REG) fusion v1.
// * R10 (3290): kA m-split 256 blocks. R11 (3203): kA 512thr (gate,k-half) = stable floor.
// * R12 (4048 REG, diagnostic): gap ~5us/launch; kA ~23us; kB+kC ~23us combined.
// * R13 (4215 REG): kA K-split 70KB LDS -> half CUs. R14 (3194): XCD pair swizzle NULL.
// * R15 (CONTAINER FAILED x2): audit found no fault (remaps bijective, ldnt can't hang,
//   no new sync). Suspect infra/poisoned node per R6 precedent.
// * R16 (this): resubmit R15 with cvt_all reverted to proven h16x2 body (only de-risk).
//   Hypothesis unchanged: (a) kA weight loads non-temporal (no cross-step reuse; stop
//   flushing 4MB/XCD L2 with the 67MB/step stream); (b) kB e-dot blocks n=i*64+b and kC
//   blocks bid=q*64+b pin XCD = b%8 so eph[b]/ecbh[b]/wcomb_b slices stay L2-resident
//   across all 48 steps. Pure cache hints + index permutations — bit-identical math.
// * Numerics: fp16 MFMA fp32-acc, c-state fp32, fp32 h2f for e-dot (proven 0.0117 schedule).

#include <hip/hip_runtime.h>

static constexpr int Bn = 64, Ln = 128, Tn = 48, En = 512, HEn = 1024, Hn = 1024, Gn = 4096;

typedef _Float16 h16;
typedef __attribute__((ext_vector_type(8))) _Float16 h16x8;
typedef __attribute__((ext_vector_type(2))) _Float16 h16x2;
typedef __attribute__((ext_vector_type(4))) float f32x4;

__device__ __forceinline__ float sigf(float x){ return 1.f / (1.f + expf(-x)); }

__device__ __forceinline__ h16x8 ldnt(const h16* p){
#if __has_builtin(__builtin_nontemporal_load)
  return __builtin_nontemporal_load(reinterpret_cast<const h16x8*>(p));
#else
  return *reinterpret_cast<const h16x8*>(p);
#endif
}

// ---------------- fused fp32 -> fp16 conversion (all 8 arrays, one launch) ----------------
struct CvtJobs {
  const float* src[8];
  h16x2* dst[8];
  int n2[8];
};

__global__ void cvt_all(CvtJobs jobs){
  int stride = gridDim.x * blockDim.x;
  int gid = blockIdx.x * blockDim.x + threadIdx.x;
  #pragma unroll
  for (int s = 0; s < 8; s++){
    const float* src = jobs.src[s];
    h16x2* dst = jobs.dst[s];
    int n2 = jobs.n2[s];
    for (int i = gid; i < n2; i += stride){
      float2 v = reinterpret_cast<const float2*>(src)[i];
      h16x2 o; o.x = (h16)v.x; o.y = (h16)v.y;
      dst[i] = o;
    }
  }
}

// ---------------- state init ----------------
__global__ void init_state(const float* __restrict__ h1i, const float* __restrict__ c1i,
                           const float* __restrict__ h2i, const float* __restrict__ c2i,
                           h16* __restrict__ h1a, float* __restrict__ c1,
                           h16* __restrict__ h2a, float* __restrict__ c2,
                           float* __restrict__ h2f, h16* __restrict__ oh){
  int i = blockIdx.x * blockDim.x + threadIdx.x;
  if (i < Bn * Hn){
    h1a[i] = (h16)h1i[i]; c1[i] = c1i[i];
    h2a[i] = (h16)h2i[i]; c2[i] = c2i[i];
    h2f[i] = h2i[i];
    oh[i] = (h16)0.f;
  }
}

// ---------------- gemm_lds: 128x128 tile, BK=32, double-buffered LDS ----------------
__global__ __launch_bounds__(256, 2) void gemm_lds(
    const h16* __restrict__ A, int lda,
    const h16* __restrict__ Bw, int ldb,
    const float* __restrict__ bias0, const float* __restrict__ bias1,
    float* __restrict__ outF, h16* __restrict__ outH, int ldc, int K)
{
  __shared__ __align__(16) h16 sA[2][4096];   // 8KB per buffer
  __shared__ __align__(16) h16 sB[2][4096];
  int tid = threadIdx.x;
  int w = tid >> 6, lane = tid & 63;
  int la = lane & 15, q = lane >> 4;
  int wr = w >> 1, wc = w & 1;
  int m0 = blockIdx.x * 128, n0 = blockIdx.y * 128;

  int srow = tid >> 2, sq = tid & 3;
  const h16* gAa = A + (size_t)(m0 + srow) * lda + sq * 8;
  const h16* gAb = gAa + (size_t)64 * lda;
  const h16* gBa = Bw + (size_t)(n0 + srow) * ldb + sq * 8;
  const h16* gBb = gBa + (size_t)64 * ldb;
  int dO = sq * 1024 + srow * 8;                 // h16 offset in [q][row] layout

  f32x4 acc[4][4];
  #pragma unroll
  for (int i = 0; i < 4; i++)
    #pragma unroll
    for (int j = 0; j < 4; j++) acc[i][j] = (f32x4){0.f, 0.f, 0.f, 0.f};

  h16x8 rAa, rAb, rBa, rBb;
  auto GLOAD = [&](int kt){
    int k0 = kt * 32;
    rAa = *reinterpret_cast<const h16x8*>(gAa + k0);
    rAb = *reinterpret_cast<const h16x8*>(gAb + k0);
    rBa = *reinterpret_cast<const h16x8*>(gBa + k0);
    rBb = *reinterpret_cast<const h16x8*>(gBb + k0);
  };
  auto SWRITE = [&](int buf){
    *reinterpret_cast<h16x8*>(&sA[buf][dO])       = rAa;
    *reinterpret_cast<h16x8*>(&sA[buf][dO + 512]) = rAb;   // rows 64..127
    *reinterpret_cast<h16x8*>(&sB[buf][dO])       = rBa;
    *reinterpret_cast<h16x8*>(&sB[buf][dO + 512]) = rBb;
  };

  int NT = K / 32;
  GLOAD(0); SWRITE(0);
  GLOAD(1);
  __syncthreads();
  for (int t = 0; t < NT; t++){
    int buf = t & 1;
    h16x8 af[4], bf[4];
    #pragma unroll
    for (int mi = 0; mi < 4; mi++)
      af[mi] = *reinterpret_cast<const h16x8*>(&sA[buf][q * 1024 + (wr * 64 + mi * 16 + la) * 8]);
    #pragma unroll
    for (int ni = 0; ni < 4; ni++)
      bf[ni] = *reinterpret_cast<const h16x8*>(&sB[buf][q * 1024 + (wc * 64 + ni * 16 + la) * 8]);
    #pragma unroll
    for (int mi = 0; mi < 4; mi++)
      #pragma unroll
      for (int ni = 0; ni < 4; ni++)
        acc[mi][ni] = __builtin_amdgcn_mfma_f32_16x16x32_f16(af[mi], bf[ni], acc[mi][ni], 0, 0, 0);
    if (t + 1 < NT){
      __syncthreads();                // everyone done reading buf[(t+1)&1] (read at t-1)
      SWRITE((t + 1) & 1);
      if (t + 2 < NT) GLOAD(t + 2);
      __syncthreads();                // writes visible before next compute
    }
  }

  #pragma unroll
  for (int mi = 0; mi < 4; mi++){
    int mrow = m0 + wr * 64 + mi * 16 + q * 4;
    #pragma unroll
    for (int ni = 0; ni < 4; ni++){
      int n = n0 + wc * 64 + ni * 16 + la;
      float bs = (bias0 ? bias0[n] : 0.f) + (bias1 ? bias1[n] : 0.f);
      #pragma unroll
      for (int r = 0; r < 4; r++){
        float v = acc[mi][ni][r] + bs;
        size_t off = (size_t)(mrow + r) * ldc + n;
        if (outF) outF[off] = v;
        else      outH[off] = (h16)v;
      }
    }
  }
}

// ---------------- 4-m-tile prefetched segment helper (kB hw GEMM; B cached) ----------------
struct PBuf { h16x8 a0, a1, a2, a3, b; };

__device__ __forceinline__ void pld(PBuf& p, const h16* __restrict__ Ap,
                                    const h16* __restrict__ Bp, int k){
  p.a0 = *reinterpret_cast<const h16x8*>(Ap + k);
  p.a1 = *reinterpret_cast<const h16x8*>(Ap + 16 * Hn + k);
  p.a2 = *reinterpret_cast<const h16x8*>(Ap + 32 * Hn + k);
  p.a3 = *reinterpret_cast<const h16x8*>(Ap + 48 * Hn + k);
  p.b  = *reinterpret_cast<const h16x8*>(Bp + k);
}
__device__ __forceinline__ void pmm(const PBuf& p, f32x4* acc){
  acc[0] = __builtin_amdgcn_mfma_f32_16x16x32_f16(p.a0, p.b, acc[0], 0, 0, 0);
  acc[1] = __builtin_amdgcn_mfma_f32_16x16x32_f16(p.a1, p.b, acc[1], 0, 0, 0);
  acc[2] = __builtin_amdgcn_mfma_f32_16x16x32_f16(p.a2, p.b, acc[2], 0, 0, 0);
  acc[3] = __builtin_amdgcn_mfma_f32_16x16x32_f16(p.a3, p.b, acc[3], 0, 0, 0);
}

template<int NS>
__device__ __forceinline__ void gseg_pf(const h16* __restrict__ Ap,
                                        const h16* __restrict__ Bp, f32x4* acc){
  PBuf p0, p1, p2, p3;
  pld(p0, Ap, Bp, 0);
  pld(p1, Ap, Bp, 32);
  pld(p2, Ap, Bp, 64);
  pld(p3, Ap, Bp, 96);
  #pragma unroll 1
  for (int s = 0; s + 4 < NS; s += 4){
    pmm(p0, acc); pld(p0, Ap, Bp, (s + 4) * 32);
    pmm(p1, acc); pld(p1, Ap, Bp, (s + 5) * 32);
    pmm(p2, acc); pld(p2, Ap, Bp, (s + 6) * 32);
    pmm(p3, acc); pld(p3, Ap, Bp, (s + 7) * 32);
  }
  pmm(p0, acc); pmm(p1, acc); pmm(p2, acc); pmm(p3, acc);
}

// ---------------- 2-m-tile prefetched segment helper (kA; WEIGHTS NON-TEMPORAL) ------------
struct PBuf2 { h16x8 a0, a1, b; };

__device__ __forceinline__ void pld2(PBuf2& p, const h16* __restrict__ Ap,
                                     const h16* __restrict__ Bp, int k){
  p.a0 = *reinterpret_cast<const h16x8*>(Ap + k);
  p.a1 = *reinterpret_cast<const h16x8*>(Ap + 16 * Hn + k);
  p.b  = ldnt(Bp + k);                         // weights: no cross-step reuse -> bypass L2
}
__device__ __forceinline__ void pmm2(const PBuf2& p, f32x4* acc){
  acc[0] = __builtin_amdgcn_mfma_f32_16x16x32_f16(p.a0, p.b, acc[0], 0, 0, 0);
  acc[1] = __builtin_amdgcn_mfma_f32_16x16x32_f16(p.a1, p.b, acc[1], 0, 0, 0);
}

template<int NS>
__device__ __forceinline__ void gseg2_pf(const h16* __restrict__ Ap,
                                         const h16* __restrict__ Bp, f32x4* acc){
  PBuf2 p0, p1, p2, p3;
  pld2(p0, Ap, Bp, 0);
  pld2(p1, Ap, Bp, 32);
  pld2(p2, Ap, Bp, 64);
  pld2(p3, Ap, Bp, 96);
  #pragma unroll 1
  for (int s = 0; s + 4 < NS; s += 4){
    pmm2(p0, acc); pld2(p0, Ap, Bp, (s + 4) * 32);
    pmm2(p1, acc); pld2(p1, Ap, Bp, (s + 5) * 32);
    pmm2(p2, acc); pld2(p2, Ap, Bp, (s + 6) * 32);
    pmm2(p3, acc); pld2(p3, Ap, Bp, (s + 7) * 32);
  }
  pmm2(p0, acc); pmm2(p1, acc); pmm2(p2, acc); pmm2(p3, acc);
}

// ---------------- kA: R11 structure (512 thr, wave=(gate,k-half)), nt weights -------------
// mode 0 (prime, 128 blocks): all g1. mode 1 (256 blocks): bid<128 is2, bid>=128 g1.
__global__ __launch_bounds__(512, 1) void kA(
    const h16* __restrict__ h1cur, const h16* __restrict__ h2prev, const h16* __restrict__ oh,
    h16* __restrict__ h1next, h16* __restrict__ h2cur, float* __restrict__ h2f,
    float* __restrict__ c1, float* __restrict__ c2,
    const h16* __restrict__ wih2, const h16* __restrict__ whh2, const h16* __restrict__ whh1,
    const float* __restrict__ bih2, const float* __restrict__ bhh2,
    const float* __restrict__ pre1_t, int mode)
{
  __shared__ float sg[4][2][32][17];           // 17.4 KB
  int bid = blockIdx.x, tid = threadIdx.x;
  int wv = tid >> 6, lane = tid & 63;
  int g = wv & 3, kh = wv >> 2;
  int la = lane & 15, q = lane >> 4;
  bool is2 = (mode == 1) && (bid < 128);
  int unit = is2 ? bid : (mode == 1 ? bid - 128 : bid);
  int jb = unit & 63, mh = unit >> 6;
  int j0 = jb * 16;
  int r0 = mh * 32;
  bool active = is2 || (pre1_t != nullptr);

  if (active){
    f32x4 acc[2];
    acc[0] = (f32x4){0.f, 0.f, 0.f, 0.f};
    acc[1] = (f32x4){0.f, 0.f, 0.f, 0.f};
    int n0 = g * 1024 + j0;
    size_t aoff = (size_t)(r0 + la) * Hn + q * 8;
    if (is2){
      // flat K = [h1(t) | o(t-1) | h2(t-1)]; wih2 cols [0,2048), whh2 cols [0,1024)
      if (kh == 0){
        gseg2_pf<32>(h1cur + aoff, wih2 + (size_t)(n0 + la) * 2048 + q * 8,        acc);
        gseg2_pf<16>(oh    + aoff, wih2 + (size_t)(n0 + la) * 2048 + 1024 + q * 8, acc);
      } else {
        gseg2_pf<16>(oh     + aoff + 512, wih2 + (size_t)(n0 + la) * 2048 + 1536 + q * 8, acc);
        gseg2_pf<32>(h2prev + aoff,       whh2 + (size_t)(n0 + la) * 1024 + q * 8,        acc);
      }
    } else {
      if (kh == 0)
        gseg2_pf<16>(h1cur + aoff,       whh1 + (size_t)(n0 + la) * 1024 + q * 8,       acc);
      else
        gseg2_pf<16>(h1cur + aoff + 512, whh1 + (size_t)(n0 + la) * 1024 + 512 + q * 8, acc);
    }
    #pragma unroll
    for (int mi = 0; mi < 2; mi++)
      #pragma unroll
      for (int r = 0; r < 4; r++)
        sg[g][kh][mi * 16 + q * 4 + r][la] = acc[mi][r];
  }
  __syncthreads();
  if (active && tid < 512){
    int e = tid;                               // 512 elements, one per thread
    int rl = e >> 4, col = e & 15, j = j0 + col;
    int row = r0 + rl;
    float gi = sg[0][0][rl][col] + sg[0][1][rl][col];
    float gf = sg[1][0][rl][col] + sg[1][1][rl][col];
    float gg = sg[2][0][rl][col] + sg[2][1][rl][col];
    float go = sg[3][0][rl][col] + sg[3][1][rl][col];
    if (is2){
      gi += bih2[j] + bhh2[j];
      gf += bih2[j + 1024] + bhh2[j + 1024];
      gg += bih2[j + 2048] + bhh2[j + 2048];
      go += bih2[j + 3072] + bhh2[j + 3072];
      float c_ = sigf(gf) * c2[row * Hn + j] + sigf(gi) * tanhf(gg);
      c2[row * Hn + j] = c_;
      float h_ = sigf(go) * tanhf(c_);
      h2cur[row * Hn + j] = (h16)h_;
      h2f[row * Hn + j] = h_;
    } else {
      const float* p = pre1_t + (size_t)row * Gn;   // includes bih1+bhh1
      gi += p[j]; gf += p[j + 1024]; gg += p[j + 2048]; go += p[j + 3072];
      float c_ = sigf(gf) * c1[row * Hn + j] + sigf(gi) * tanhf(gg);
      c1[row * Hn + j] = c_;
      h1next[row * Hn + j] = (h16)(sigf(go) * tanhf(c_));
    }
  }
}

// ---------------- kB: hw GEMM (blocks 0-15) || e-dots b-pinned to XCDs (blocks 16-2063) ----
// e-dot block n=bid-16: b = n&63, l = (n>>6)*4+w. XCD = bid%8 tracks b%8, so all readers of
// eph[b] hit the same XCD's L2 every step (per-XCD slice ~2MB, stays resident).
__global__ __launch_bounds__(256, 2) void kB(
    const float* __restrict__ h2f, const h16* __restrict__ eph, const int* __restrict__ msk,
    float* __restrict__ ebuf,
    const h16* __restrict__ h2cur, const h16* __restrict__ wcomb, const float* __restrict__ bcomb,
    float* __restrict__ hwb)
{
  int bid = blockIdx.x, tid = threadIdx.x;
  int w = tid >> 6, lane = tid & 63;
  if (bid >= 16){
    int n = bid - 16;               // 0..2047
    int b = n & 63;
    int l = (n >> 6) * 4 + w;       // 0..127
    const f32x4* h2r = reinterpret_cast<const f32x4*>(h2f + (size_t)b * Hn + lane * 16);
    f32x4 hv0 = h2r[0], hv1 = h2r[1], hv2 = h2r[2], hv3 = h2r[3];
    const h16x8* er = reinterpret_cast<const h16x8*>(eph + ((size_t)b * Ln + l) * Hn + lane * 16);
    h16x8 e0 = er[0], e1 = er[1];
    float acc = 0.f;
    #pragma unroll
    for (int i = 0; i < 4; i++) acc += hv0[i] * (float)e0[i];
    #pragma unroll
    for (int i = 0; i < 4; i++) acc += hv1[i] * (float)e0[4 + i];
    #pragma unroll
    for (int i = 0; i < 4; i++) acc += hv2[i] * (float)e1[i];
    #pragma unroll
    for (int i = 0; i < 4; i++) acc += hv3[i] * (float)e1[4 + i];
    for (int off = 32; off; off >>= 1) acc += __shfl_xor(acc, off);
    if (lane == 0) ebuf[b * Ln + l] = msk[b * Ln + l] ? -1e30f : acc;
  } else {
    int hb = bid;                   // 0..15 (fixed bids -> same XCD every step; wcomb_b
    int la = lane & 15, q = lane >> 4;          //  slice ~131KB/block stays L2-resident)
    int n0 = hb * 64 + w * 16;
    f32x4 acc[4];
    #pragma unroll
    for (int mi = 0; mi < 4; mi++) acc[mi] = (f32x4){0.f, 0.f, 0.f, 0.f};
    gseg_pf<32>(h2cur + la * Hn + q * 8,
                wcomb + (size_t)(n0 + la) * (HEn + Hn) + HEn + q * 8, acc);
    float bs = bcomb[n0 + la];
    #pragma unroll
    for (int mi = 0; mi < 4; mi++)
      #pragma unroll
      for (int r = 0; r < 4; r++)
        hwb[(size_t)(mi * 16 + q * 4 + r) * Hn + n0 + la] = acc[mi][r] + bs;
  }
}

// ---------------- kC: softmax + gather, b-pinned to XCDs -----------------------------------
// bid = q*64 + b (b = bid&63, q = bid>>6): XCD tracks b%8, ecbh[b] slice stays L2-resident.
__global__ __launch_bounds__(256, 2) void kC(
    int t, const float* __restrict__ ebuf,
    const h16* __restrict__ ecbh, const float* __restrict__ hwb,
    float* __restrict__ out, h16* __restrict__ oh)
{
  __shared__ float sb[Ln];
  __shared__ float rmax[4], rsum[4];
  __shared__ float sp[128][2];
  int bid = blockIdx.x;
  int b = bid & 63;
  int jq = (bid >> 6) * 256;
  int tid = threadIdx.x;            // 0..255
  int wv = tid >> 6;
  // softmax: waves 0,1 cover l 0..127; waves 2,3 duplicate (harmless for max).
  float e = ebuf[b * Ln + (tid & 127)];
  float m = e;
  #pragma unroll
  for (int off = 32; off; off >>= 1) m = fmaxf(m, __shfl_xor(m, off));
  if ((tid & 63) == 0) rmax[wv] = m;
  __syncthreads();
  m = fmaxf(fmaxf(rmax[0], rmax[1]), fmaxf(rmax[2], rmax[3]));
  float ex = expf(e - m);
  if (tid < 128) sb[tid] = ex;
  float s = ex;
  #pragma unroll
  for (int off = 32; off; off >>= 1) s += __shfl_xor(s, off);
  if ((tid & 63) == 0) rsum[wv] = s;
  __syncthreads();
  float rinv = 1.f / (rsum[0] + rsum[1]);   // waves 2,3 are duplicates — excluded

  int col = tid & 127, lh = tid >> 7;
  int j0 = jq + col * 2;
  const h16* base = ecbh + (size_t)b * Ln * Hn + j0;
  float a0 = 0.f, a1 = 0.f, c0 = 0.f, c1 = 0.f;
  int lb = lh * 64;
  #pragma unroll 8
  for (int i = 0; i < 64; i += 2){
    int l = lb + i;
    float al0 = sb[l], al1 = sb[l + 1];
    h16x2 p0 = *reinterpret_cast<const h16x2*>(base + (size_t)l * Hn);
    h16x2 p1 = *reinterpret_cast<const h16x2*>(base + (size_t)(l + 1) * Hn);
    a0 += al0 * (float)p0.x; a1 += al0 * (float)p0.y;
    c0 += al1 * (float)p1.x; c1 += al1 * (float)p1.y;
  }
  float t0 = a0 + c0, t1 = a1 + c1;
  if (lh == 1){ sp[col][0] = t0; sp[col][1] = t1; }
  __syncthreads();
  if (lh == 0){
    float g0 = (t0 + sp[col][0]) * rinv;
    float g1 = (t1 + sp[col][1]) * rinv;
    float2 hw2 = *reinterpret_cast<const float2*>(hwb + b * Hn + j0);   // bias included
    float o0 = tanhf(g0 + hw2.x);
    float o1 = tanhf(g1 + hw2.y);
    *reinterpret_cast<float2*>(out + ((size_t)t * Bn + b) * Hn + j0) = make_float2(o0, o1);
    h16x2 opk; opk.x = (h16)o0; opk.y = (h16)o1;
    *reinterpret_cast<h16x2*>(oh + (size_t)b * Hn + j0) = opk;
  }
}

// ---------------- host ----------------
extern "C" void kernel_launch(void* const* d_in, const int* in_sizes, int n_in,
                              void* d_out, int out_size, void* d_ws, size_t ws_size,
                              hipStream_t stream)
{
  const float* enc   = (const float*)d_in[0];
  const int*   msk   = (const int*)  d_in[1];
  const float* h1i   = (const float*)d_in[2];
  const float* c1i   = (const float*)d_in[3];
  const float* h2i   = (const float*)d_in[4];
  const float* c2i   = (const float*)d_in[5];
  const float* caps  = (const float*)d_in[6];
  const float* Wih1  = (const float*)d_in[7];
  const float* Whh1  = (const float*)d_in[8];
  const float* bih1  = (const float*)d_in[9];
  const float* bhh1  = (const float*)d_in[10];
  const float* Wih2  = (const float*)d_in[11];
  const float* Whh2  = (const float*)d_in[12];
  const float* bih2  = (const float*)d_in[13];
  const float* bhh2  = (const float*)d_in[14];
  const float* Watt  = (const float*)d_in[15];
  const float* batt  = (const float*)d_in[16];
  const float* Wcomb = (const float*)d_in[17];
  const float* bcomb = (const float*)d_in[18];
  float* out = (float*)d_out;

  char* p = (char*)d_ws;
  auto take = [&](size_t bytes){ char* r = p; p += (bytes + 255) & ~(size_t)255; return r; };
  float* pre1   = (float*)take((size_t)Tn * Bn * Gn * 4);          // 50.3 MB
  h16*   ench   = (h16*)take((size_t)Bn * Ln * HEn * 2);
  h16*   eph    = (h16*)take((size_t)Bn * Ln * Hn * 2);
  h16*   ecbh   = (h16*)take((size_t)Bn * Ln * Hn * 2);
  h16*   caph   = (h16*)take((size_t)Tn * Bn * En * 2);
  h16*   wih1h  = (h16*)take((size_t)Gn * En * 2);
  h16*   whh1h  = (h16*)take((size_t)Gn * Hn * 2);
  h16*   wih2h  = (h16*)take((size_t)Gn * 2 * Hn * 2);
  h16*   whh2h  = (h16*)take((size_t)Gn * Hn * 2);
  h16*   watth  = (h16*)take((size_t)Hn * HEn * 2);
  h16*   wcombh = (h16*)take((size_t)Hn * (HEn + Hn) * 2);
  h16*   h1b0   = (h16*)take((size_t)Bn * Hn * 2);
  h16*   h1b1   = (h16*)take((size_t)Bn * Hn * 2);
  h16*   h2b0   = (h16*)take((size_t)Bn * Hn * 2);
  h16*   h2b1   = (h16*)take((size_t)Bn * Hn * 2);
  h16*   oh     = (h16*)take((size_t)Bn * Hn * 2);
  float* c1     = (float*)take((size_t)Bn * Hn * 4);
  float* c2     = (float*)take((size_t)Bn * Hn * 4);
  float* h2f    = (float*)take((size_t)Bn * Hn * 4);
  float* ebuf   = (float*)take((size_t)Bn * Ln * 4);
  float* hwb    = (float*)take((size_t)Bn * Hn * 4);
  (void)ws_size; (void)n_in; (void)in_sizes; (void)out_size;

  CvtJobs jobs;
  jobs.src[0] = enc;   jobs.dst[0] = (h16x2*)ench;   jobs.n2[0] = Bn * Ln * HEn / 2;
  jobs.src[1] = caps;  jobs.dst[1] = (h16x2*)caph;   jobs.n2[1] = Tn * Bn * En / 2;
  jobs.src[2] = Wih1;  jobs.dst[2] = (h16x2*)wih1h;  jobs.n2[2] = Gn * En / 2;
  jobs.src[3] = Whh1;  jobs.dst[3] = (h16x2*)whh1h;  jobs.n2[3] = Gn * Hn / 2;
  jobs.src[4] = Wih2;  jobs.dst[4] = (h16x2*)wih2h;  jobs.n2[4] = Gn * 2 * Hn / 2;
  jobs.src[5] = Whh2;  jobs.dst[5] = (h16x2*)whh2h;  jobs.n2[5] = Gn * Hn / 2;
  jobs.src[6] = Watt;  jobs.dst[6] = (h16x2*)watth;  jobs.n2[6] = Hn * HEn / 2;
  jobs.src[7] = Wcomb; jobs.dst[7] = (h16x2*)wcombh; jobs.n2[7] = Hn * (HEn + Hn) / 2;
  cvt_all<<<2048, 256, 0, stream>>>(jobs);

  init_state<<<(Bn * Hn) / 256, 256, 0, stream>>>(h1i, c1i, h2i, c2i,
                                                  h1b0, c1, h2b0, c2, h2f, oh);

  // pre1 = captions @ Wih1^T + bih1 + bhh1   (3072 x 4096, K=512)
  gemm_lds<<<dim3((Tn * Bn) / 128, Gn / 128), 256, 0, stream>>>(
      caph, En, wih1h, En, bih1, bhh1, pre1, nullptr, Gn, En);
  // enc_proj = enc @ Watt^T + batt  (8192 x 1024, K=1024) -> fp16
  gemm_lds<<<dim3((Bn * Ln) / 128, Hn / 128), 256, 0, stream>>>(
      ench, HEn, watth, HEn, batt, nullptr, nullptr, eph, Hn, HEn);
  // enc_comb = enc @ Wcomb[:, :HE]^T  (8192 x 1024, K=1024) -> fp16
  gemm_lds<<<dim3((Bn * Ln) / 128, Hn / 128), 256, 0, stream>>>(
      ench, HEn, wcombh, HEn + Hn, nullptr, nullptr, nullptr, ecbh, Hn, HEn);

  // prime: gates1(0) -> h1(0) in h1b1 (h1 state for t lives in h1buf[(t+1)&1])
  kA<<<128, 512, 0, stream>>>(h1b0, h2b0, oh, h1b1, h2b1, h2f, c1, c2,
                              wih2h, whh2h, whh1h, bih2, bhh2, pre1, /*mode=*/0);

  h16* h1buf[2] = { h1b0, h1b1 };
  h16* h2buf[2] = { h2b0, h2b1 };
  for (int t = 0; t < Tn; t++){
    h16* h1cur  = h1buf[(t + 1) & 1];
    h16* h1next = h1buf[t & 1];
    h16* h2prev = h2buf[t & 1];
    h16* h2cur  = h2buf[(t + 1) & 1];
    const float* pre1_t = (t + 1 < Tn) ? (pre1 + (size_t)(t + 1) * Bn * Gn) : nullptr;
    kA<<<256, 512, 0, stream>>>(h1cur, h2prev, oh, h1next, h2cur, h2f, c1, c2,
                                wih2h, whh2h, whh1h, bih2, bhh2, pre1_t, /*mode=*/1);
    kB<<<2064, 256, 0, stream>>>(h2f, eph, msk, ebuf, h2cur, wcombh, bcomb, hwb);
    kC<<<256, 256, 0, stream>>>(t, ebuf, ecbh, hwb, out, oh);
  }
}

// Round 10
// 2658.202 us; speedup vs baseline: 1.2265x; 1.2265x over previous
//
// LSTMDecoder on MI355X — round 17: kA inner loop rebuilt on the proven gemm_lds staging
// pattern (global->reg->LDS double-buffer), killing the register-prefetch collapse.
//
// Journal:
// * R2: multi-kernel PASSED 0.0117 @ 9763us. R3-R6: barrier/coop failed -> abandoned.
// * R7 (6627) gemm8 vmcnt serialization. R8 (4615) reg prefetch (collapsed: VGPR=116<144).
// * R9 (7230 REG) fusion v1. R10 (3290) kA m-split. R11 (3203) kA 512thr = plateau.
// * R12 (4048 REG, diagnostic): gap ~5us/launch; kA ~23us; VGPR=32 collapse again.
// * R13 (4215 REG): kA K-split, VGPR=44 collapse again. R14 (3194): XCD pairing NULL.
// * R15 (container died x2) vs R16 (ran): only diff was float4 cvt -> float4 on harness
//   input pointers is the prime container-death suspect. NEVER reintroduce.
// * R16 (3260): nt-weights + b-pinned kB/kC = NULL. L2-residency hypothesis refuted.
// * R17 (this): pattern across R8/R12/R13 says PBuf register rotation ALWAYS collapses
//   (3 strikes, VGPR counters). If kA's is collapsed too, depth~1 -> ~0.4MB in flight
//   chip-wide -> ~2.9 TB/s observed. gemm_lds staging beat this once already (136->55us).
//   kA rebuilt: flat-K tiled 128 cols; sA[2] 8KB + sB[2] 16KB + sg = 65.4KB LDS (R13
//   proved 69.6KB runs); 3x16B staged loads/thread/tile; 2-barrier loop; wave (g,kh)
//   computes the kh-half (64 cols) of each tile. Same MFMA fragments, same epilogue.
//   kh reorder is fp32-sum-order only. kB/kC/cvt/setup = R16 verbatim.
// * Numerics: fp16 MFMA fp32-acc, c-state fp32, fp32 h2f for e-dot (proven 0.0117 schedule).

#include <hip/hip_runtime.h>

static constexpr int Bn = 64, Ln = 128, Tn = 48, En = 512, HEn = 1024, Hn = 1024, Gn = 4096;

typedef _Float16 h16;
typedef __attribute__((ext_vector_type(8))) _Float16 h16x8;
typedef __attribute__((ext_vector_type(2))) _Float16 h16x2;
typedef __attribute__((ext_vector_type(4))) float f32x4;

__device__ __forceinline__ float sigf(float x){ return 1.f / (1.f + expf(-x)); }

// ---------------- fused fp32 -> fp16 conversion (all 8 arrays, one launch) ----------------
struct CvtJobs {
  const float* src[8];
  h16x2* dst[8];
  int n2[8];
};

__global__ void cvt_all(CvtJobs jobs){
  int stride = gridDim.x * blockDim.x;
  int gid = blockIdx.x * blockDim.x + threadIdx.x;
  #pragma unroll
  for (int s = 0; s < 8; s++){
    const float* src = jobs.src[s];
    h16x2* dst = jobs.dst[s];
    int n2 = jobs.n2[s];
    for (int i = gid; i < n2; i += stride){
      float2 v = reinterpret_cast<const float2*>(src)[i];
      h16x2 o; o.x = (h16)v.x; o.y = (h16)v.y;
      dst[i] = o;
    }
  }
}

// ---------------- state init ----------------
__global__ void init_state(const float* __restrict__ h1i, const float* __restrict__ c1i,
                           const float* __restrict__ h2i, const float* __restrict__ c2i,
                           h16* __restrict__ h1a, float* __restrict__ c1,
                           h16* __restrict__ h2a, float* __restrict__ c2,
                           float* __restrict__ h2f, h16* __restrict__ oh){
  int i = blockIdx.x * blockDim.x + threadIdx.x;
  if (i < Bn * Hn){
    h1a[i] = (h16)h1i[i]; c1[i] = c1i[i];
    h2a[i] = (h16)h2i[i]; c2[i] = c2i[i];
    h2f[i] = h2i[i];
    oh[i] = (h16)0.f;
  }
}

// ---------------- gemm_lds: 128x128 tile, BK=32, double-buffered LDS ----------------
__global__ __launch_bounds__(256, 2) void gemm_lds(
    const h16* __restrict__ A, int lda,
    const h16* __restrict__ Bw, int ldb,
    const float* __restrict__ bias0, const float* __restrict__ bias1,
    float* __restrict__ outF, h16* __restrict__ outH, int ldc, int K)
{
  __shared__ __align__(16) h16 sA[2][4096];   // 8KB per buffer
  __shared__ __align__(16) h16 sB[2][4096];
  int tid = threadIdx.x;
  int w = tid >> 6, lane = tid & 63;
  int la = lane & 15, q = lane >> 4;
  int wr = w >> 1, wc = w & 1;
  int m0 = blockIdx.x * 128, n0 = blockIdx.y * 128;

  int srow = tid >> 2, sq = tid & 3;
  const h16* gAa = A + (size_t)(m0 + srow) * lda + sq * 8;
  const h16* gAb = gAa + (size_t)64 * lda;
  const h16* gBa = Bw + (size_t)(n0 + srow) * ldb + sq * 8;
  const h16* gBb = gBa + (size_t)64 * ldb;
  int dO = sq * 1024 + srow * 8;                 // h16 offset in [q][row] layout

  f32x4 acc[4][4];
  #pragma unroll
  for (int i = 0; i < 4; i++)
    #pragma unroll
    for (int j = 0; j < 4; j++) acc[i][j] = (f32x4){0.f, 0.f, 0.f, 0.f};

  h16x8 rAa, rAb, rBa, rBb;
  auto GLOAD = [&](int kt){
    int k0 = kt * 32;
    rAa = *reinterpret_cast<const h16x8*>(gAa + k0);
    rAb = *reinterpret_cast<const h16x8*>(gAb + k0);
    rBa = *reinterpret_cast<const h16x8*>(gBa + k0);
    rBb = *reinterpret_cast<const h16x8*>(gBb + k0);
  };
  auto SWRITE = [&](int buf){
    *reinterpret_cast<h16x8*>(&sA[buf][dO])       = rAa;
    *reinterpret_cast<h16x8*>(&sA[buf][dO + 512]) = rAb;   // rows 64..127
    *reinterpret_cast<h16x8*>(&sB[buf][dO])       = rBa;
    *reinterpret_cast<h16x8*>(&sB[buf][dO + 512]) = rBb;
  };

  int NT = K / 32;
  GLOAD(0); SWRITE(0);
  GLOAD(1);
  __syncthreads();
  for (int t = 0; t < NT; t++){
    int buf = t & 1;
    h16x8 af[4], bf[4];
    #pragma unroll
    for (int mi = 0; mi < 4; mi++)
      af[mi] = *reinterpret_cast<const h16x8*>(&sA[buf][q * 1024 + (wr * 64 + mi * 16 + la) * 8]);
    #pragma unroll
    for (int ni = 0; ni < 4; ni++)
      bf[ni] = *reinterpret_cast<const h16x8*>(&sB[buf][q * 1024 + (wc * 64 + ni * 16 + la) * 8]);
    #pragma unroll
    for (int mi = 0; mi < 4; mi++)
      #pragma unroll
      for (int ni = 0; ni < 4; ni++)
        acc[mi][ni] = __builtin_amdgcn_mfma_f32_16x16x32_f16(af[mi], bf[ni], acc[mi][ni], 0, 0, 0);
    if (t + 1 < NT){
      __syncthreads();                // everyone done reading buf[(t+1)&1] (read at t-1)
      SWRITE((t + 1) & 1);
      if (t + 2 < NT) GLOAD(t + 2);
      __syncthreads();                // writes visible before next compute
    }
  }

  #pragma unroll
  for (int mi = 0; mi < 4; mi++){
    int mrow = m0 + wr * 64 + mi * 16 + q * 4;
    #pragma unroll
    for (int ni = 0; ni < 4; ni++){
      int n = n0 + wc * 64 + ni * 16 + la;
      float bs = (bias0 ? bias0[n] : 0.f) + (bias1 ? bias1[n] : 0.f);
      #pragma unroll
      for (int r = 0; r < 4; r++){
        float v = acc[mi][ni][r] + bs;
        size_t off = (size_t)(mrow + r) * ldc + n;
        if (outF) outF[off] = v;
        else      outH[off] = (h16)v;
      }
    }
  }
}

// ---------------- 4-m-tile prefetched segment helper (kB hw GEMM) ----------------
struct PBuf { h16x8 a0, a1, a2, a3, b; };

__device__ __forceinline__ void pld(PBuf& p, const h16* __restrict__ Ap,
                                    const h16* __restrict__ Bp, int k){
  p.a0 = *reinterpret_cast<const h16x8*>(Ap + k);
  p.a1 = *reinterpret_cast<const h16x8*>(Ap + 16 * Hn + k);
  p.a2 = *reinterpret_cast<const h16x8*>(Ap + 32 * Hn + k);
  p.a3 = *reinterpret_cast<const h16x8*>(Ap + 48 * Hn + k);
  p.b  = *reinterpret_cast<const h16x8*>(Bp + k);
}
__device__ __forceinline__ void pmm(const PBuf& p, f32x4* acc){
  acc[0] = __builtin_amdgcn_mfma_f32_16x16x32_f16(p.a0, p.b, acc[0], 0, 0, 0);
  acc[1] = __builtin_amdgcn_mfma_f32_16x16x32_f16(p.a1, p.b, acc[1], 0, 0, 0);
  acc[2] = __builtin_amdgcn_mfma_f32_16x16x32_f16(p.a2, p.b, acc[2], 0, 0, 0);
  acc[3] = __builtin_amdgcn_mfma_f32_16x16x32_f16(p.a3, p.b, acc[3], 0, 0, 0);
}

template<int NS>
__device__ __forceinline__ void gseg_pf(const h16* __restrict__ Ap,
                                        const h16* __restrict__ Bp, f32x4* acc){
  PBuf p0, p1, p2, p3;
  pld(p0, Ap, Bp, 0);
  pld(p1, Ap, Bp, 32);
  pld(p2, Ap, Bp, 64);
  pld(p3, Ap, Bp, 96);
  #pragma unroll 1
  for (int s = 0; s + 4 < NS; s += 4){
    pmm(p0, acc); pld(p0, Ap, Bp, (s + 4) * 32);
    pmm(p1, acc); pld(p1, Ap, Bp, (s + 5) * 32);
    pmm(p2, acc); pld(p2, Ap, Bp, (s + 6) * 32);
    pmm(p3, acc); pld(p3, Ap, Bp, (s + 7) * 32);
  }
  pmm(p0, acc); pmm(p1, acc); pmm(p2, acc); pmm(p3, acc);
}

// ---------------- kA: LDS-staged gates GEMM (gemm_lds pattern). --------------------------
// 256 blocks (mode 1: 128 gates2 + 128 gates1), 512 thr = 8 waves = (gate g, col-half kh).
// Block = 32 batch rows x 16 j-cols x 4 gates. Flat-K tiled by 128 cols; per tile:
// sA 32x128 (slot cc*32+row), sB 64x128 (slot cc*64+g*16+la), cc = (u*4+q) 16B chunks.
// Wave (g,kh) computes units u = kh*2, kh*2+1 of each tile (fp32 sum-order change only).
// Staging: 3 x 16B per thread per tile, global->reg->barrier->LDS (regalloc-collapse-proof).
__global__ __launch_bounds__(512, 1) void kA(
    const h16* __restrict__ h1cur, const h16* __restrict__ h2prev, const h16* __restrict__ oh,
    h16* __restrict__ h1next, h16* __restrict__ h2cur, float* __restrict__ h2f,
    float* __restrict__ c1, float* __restrict__ c2,
    const h16* __restrict__ wih2, const h16* __restrict__ whh2, const h16* __restrict__ whh1,
    const float* __restrict__ bih2, const float* __restrict__ bhh2,
    const float* __restrict__ pre1_t, int mode)
{
  __shared__ __align__(16) h16 sA[2][4096];    // 32 rows x 128 cols, 8KB per buffer
  __shared__ __align__(16) h16 sB[2][8192];    // 64 w-rows x 128 cols, 16KB per buffer
  __shared__ float sg[4][2][32][17];           // 17.4 KB -> total 65.4 KB (R13 proved 69.6)
  int bid = blockIdx.x, tid = threadIdx.x;
  int wv = tid >> 6, lane = tid & 63;
  int g = wv & 3, kh = wv >> 2;
  int la = lane & 15, q = lane >> 4;
  bool is2 = (mode == 1) && (bid < 128);
  int unit = is2 ? bid : (mode == 1 ? bid - 128 : bid);
  int jb = unit & 63, mh = unit >> 6;
  int j0 = jb * 16;
  int r0 = mh * 32;
  bool active = is2 || (pre1_t != nullptr);    // block-uniform -> barriers below are safe

  if (active){
    f32x4 acc0 = (f32x4){0.f, 0.f, 0.f, 0.f};
    f32x4 acc1 = (f32x4){0.f, 0.f, 0.f, 0.f};
    int NT = is2 ? 24 : 8;                     // flat-K / 128

    // staging thread mapping: A slot s=tid (cc=s&15, row=s>>4);
    // B slots s=tid, tid+512 (cc=s&15, grl=s>>4 with g=grl>>4, la=grl&15)
    int sa_cc = tid & 15, sa_row = tid >> 4;
    int sb_cc0 = tid & 15, sb_grl0 = tid >> 4;
    int t1 = tid + 512;
    int sb_cc1 = t1 & 15, sb_grl1 = t1 >> 4;

    h16x8 rA, rB0, rB1;
    auto GLOAD = [&](int st){
      int fc = st * 128;
      const h16* pa;
      if (!is2)            pa = h1cur + fc;
      else if (fc < 1024)  pa = h1cur + fc;
      else if (fc < 2048)  pa = oh + (fc - 1024);
      else                 pa = h2prev + (fc - 2048);
      rA = *reinterpret_cast<const h16x8*>(pa + (size_t)(r0 + sa_row) * Hn + sa_cc * 8);
      const h16* pb; int bstr;
      if (!is2){ pb = whh1 + fc; bstr = 1024; }
      else if (fc < 2048){ pb = wih2 + fc; bstr = 2048; }
      else { pb = whh2 + (fc - 2048); bstr = 1024; }
      rB0 = *reinterpret_cast<const h16x8*>(
          pb + (size_t)((sb_grl0 >> 4) * 1024 + j0 + (sb_grl0 & 15)) * bstr + sb_cc0 * 8);
      rB1 = *reinterpret_cast<const h16x8*>(
          pb + (size_t)((sb_grl1 >> 4) * 1024 + j0 + (sb_grl1 & 15)) * bstr + sb_cc1 * 8);
    };
    auto SWRITE = [&](int buf){
      *reinterpret_cast<h16x8*>(&sA[buf][(sa_cc * 32 + sa_row) * 8])  = rA;
      *reinterpret_cast<h16x8*>(&sB[buf][(sb_cc0 * 64 + sb_grl0) * 8]) = rB0;
      *reinterpret_cast<h16x8*>(&sB[buf][(sb_cc1 * 64 + sb_grl1) * 8]) = rB1;
    };

    GLOAD(0); SWRITE(0);
    GLOAD(1);
    __syncthreads();
    for (int st = 0; st < NT; st++){
      int buf = st & 1;
      #pragma unroll
      for (int uu = 0; uu < 2; uu++){
        int cc = (kh * 2 + uu) * 4 + q;        // unit u = kh*2+uu, k-cols u*32 + q*8
        h16x8 a0 = *reinterpret_cast<const h16x8*>(&sA[buf][(cc * 32 + la) * 8]);
        h16x8 a1 = *reinterpret_cast<const h16x8*>(&sA[buf][(cc * 32 + 16 + la) * 8]);
        h16x8 bf = *reinterpret_cast<const h16x8*>(&sB[buf][(cc * 64 + g * 16 + la) * 8]);
        acc0 = __builtin_amdgcn_mfma_f32_16x16x32_f16(a0, bf, acc0, 0, 0, 0);
        acc1 = __builtin_amdgcn_mfma_f32_16x16x32_f16(a1, bf, acc1, 0, 0, 0);
      }
      if (st + 1 < NT){
        __syncthreads();               // all waves done reading buf[(st+1)&1]
        SWRITE((st + 1) & 1);
        if (st + 2 < NT) GLOAD(st + 2);
        __syncthreads();               // writes visible before next compute
      }
    }
    #pragma unroll
    for (int r = 0; r < 4; r++){
      sg[g][kh][q * 4 + r][la]      = acc0[r];
      sg[g][kh][16 + q * 4 + r][la] = acc1[r];
    }
  }
  __syncthreads();
  if (active && tid < 512){
    int e = tid;                               // 512 elements, one per thread
    int rl = e >> 4, col = e & 15, j = j0 + col;
    int row = r0 + rl;
    float gi = sg[0][0][rl][col] + sg[0][1][rl][col];
    float gf = sg[1][0][rl][col] + sg[1][1][rl][col];
    float gg = sg[2][0][rl][col] + sg[2][1][rl][col];
    float go = sg[3][0][rl][col] + sg[3][1][rl][col];
    if (is2){
      gi += bih2[j] + bhh2[j];
      gf += bih2[j + 1024] + bhh2[j + 1024];
      gg += bih2[j + 2048] + bhh2[j + 2048];
      go += bih2[j + 3072] + bhh2[j + 3072];
      float c_ = sigf(gf) * c2[row * Hn + j] + sigf(gi) * tanhf(gg);
      c2[row * Hn + j] = c_;
      float h_ = sigf(go) * tanhf(c_);
      h2cur[row * Hn + j] = (h16)h_;
      h2f[row * Hn + j] = h_;
    } else {
      const float* p = pre1_t + (size_t)row * Gn;   // includes bih1+bhh1
      gi += p[j]; gf += p[j + 1024]; gg += p[j + 2048]; go += p[j + 3072];
      float c_ = sigf(gf) * c1[row * Hn + j] + sigf(gi) * tanhf(gg);
      c1[row * Hn + j] = c_;
      h1next[row * Hn + j] = (h16)(sigf(go) * tanhf(c_));
    }
  }
}

// ---------------- kB: hw GEMM (blocks 0-15) || e-dots b-pinned to XCDs (blocks 16-2063) ----
__global__ __launch_bounds__(256, 2) void kB(
    const float* __restrict__ h2f, const h16* __restrict__ eph, const int* __restrict__ msk,
    float* __restrict__ ebuf,
    const h16* __restrict__ h2cur, const h16* __restrict__ wcomb, const float* __restrict__ bcomb,
    float* __restrict__ hwb)
{
  int bid = blockIdx.x, tid = threadIdx.x;
  int w = tid >> 6, lane = tid & 63;
  if (bid >= 16){
    int n = bid - 16;               // 0..2047
    int b = n & 63;
    int l = (n >> 6) * 4 + w;       // 0..127
    const f32x4* h2r = reinterpret_cast<const f32x4*>(h2f + (size_t)b * Hn + lane * 16);
    f32x4 hv0 = h2r[0], hv1 = h2r[1], hv2 = h2r[2], hv3 = h2r[3];
    const h16x8* er = reinterpret_cast<const h16x8*>(eph + ((size_t)b * Ln + l) * Hn + lane * 16);
    h16x8 e0 = er[0], e1 = er[1];
    float acc = 0.f;
    #pragma unroll
    for (int i = 0; i < 4; i++) acc += hv0[i] * (float)e0[i];
    #pragma unroll
    for (int i = 0; i < 4; i++) acc += hv1[i] * (float)e0[4 + i];
    #pragma unroll
    for (int i = 0; i < 4; i++) acc += hv2[i] * (float)e1[i];
    #pragma unroll
    for (int i = 0; i < 4; i++) acc += hv3[i] * (float)e1[4 + i];
    for (int off = 32; off; off >>= 1) acc += __shfl_xor(acc, off);
    if (lane == 0) ebuf[b * Ln + l] = msk[b * Ln + l] ? -1e30f : acc;
  } else {
    int hb = bid;                   // 0..15
    int la = lane & 15, q = lane >> 4;
    int n0 = hb * 64 + w * 16;
    f32x4 acc[4];
    #pragma unroll
    for (int mi = 0; mi < 4; mi++) acc[mi] = (f32x4){0.f, 0.f, 0.f, 0.f};
    gseg_pf<32>(h2cur + la * Hn + q * 8,
                wcomb + (size_t)(n0 + la) * (HEn + Hn) + HEn + q * 8, acc);
    float bs = bcomb[n0 + la];
    #pragma unroll
    for (int mi = 0; mi < 4; mi++)
      #pragma unroll
      for (int r = 0; r < 4; r++)
        hwb[(size_t)(mi * 16 + q * 4 + r) * Hn + n0 + la] = acc[mi][r] + bs;
  }
}

// ---------------- kC: softmax + gather, b-pinned to XCDs -----------------------------------
__global__ __launch_bounds__(256, 2) void kC(
    int t, const float* __restrict__ ebuf,
    const h16* __restrict__ ecbh, const float* __restrict__ hwb,
    float* __restrict__ out, h16* __restrict__ oh)
{
  __shared__ float sb[Ln];
  __shared__ float rmax[4], rsum[4];
  __shared__ float sp[128][2];
  int bid = blockIdx.x;
  int b = bid & 63;
  int jq = (bid >> 6) * 256;
  int tid = threadIdx.x;            // 0..255
  int wv = tid >> 6;
  // softmax: waves 0,1 cover l 0..127; waves 2,3 duplicate (harmless for max).
  float e = ebuf[b * Ln + (tid & 127)];
  float m = e;
  #pragma unroll
  for (int off = 32; off; off >>= 1) m = fmaxf(m, __shfl_xor(m, off));
  if ((tid & 63) == 0) rmax[wv] = m;
  __syncthreads();
  m = fmaxf(fmaxf(rmax[0], rmax[1]), fmaxf(rmax[2], rmax[3]));
  float ex = expf(e - m);
  if (tid < 128) sb[tid] = ex;
  float s = ex;
  #pragma unroll
  for (int off = 32; off; off >>= 1) s += __shfl_xor(s, off);
  if ((tid & 63) == 0) rsum[wv] = s;
  __syncthreads();
  float rinv = 1.f / (rsum[0] + rsum[1]);   // waves 2,3 are duplicates — excluded

  int col = tid & 127, lh = tid >> 7;
  int j0 = jq + col * 2;
  const h16* base = ecbh + (size_t)b * Ln * Hn + j0;
  float a0 = 0.f, a1 = 0.f, c0 = 0.f, c1 = 0.f;
  int lb = lh * 64;
  #pragma unroll 8
  for (int i = 0; i < 64; i += 2){
    int l = lb + i;
    float al0 = sb[l], al1 = sb[l + 1];
    h16x2 p0 = *reinterpret_cast<const h16x2*>(base + (size_t)l * Hn);
    h16x2 p1 = *reinterpret_cast<const h16x2*>(base + (size_t)(l + 1) * Hn);
    a0 += al0 * (float)p0.x; a1 += al0 * (float)p0.y;
    c0 += al1 * (float)p1.x; c1 += al1 * (float)p1.y;
  }
  float t0 = a0 + c0, t1 = a1 + c1;
  if (lh == 1){ sp[col][0] = t0; sp[col][1] = t1; }
  __syncthreads();
  if (lh == 0){
    float g0 = (t0 + sp[col][0]) * rinv;
    float g1 = (t1 + sp[col][1]) * rinv;
    float2 hw2 = *reinterpret_cast<const float2*>(hwb + b * Hn + j0);   // bias included
    float o0 = tanhf(g0 + hw2.x);
    float o1 = tanhf(g1 + hw2.y);
    *reinterpret_cast<float2*>(out + ((size_t)t * Bn + b) * Hn + j0) = make_float2(o0, o1);
    h16x2 opk; opk.x = (h16)o0; opk.y = (h16)o1;
    *reinterpret_cast<h16x2*>(oh + (size_t)b * Hn + j0) = opk;
  }
}

// ---------------- host ----------------
extern "C" void kernel_launch(void* const* d_in, const int* in_sizes, int n_in,
                              void* d_out, int out_size, void* d_ws, size_t ws_size,
                              hipStream_t stream)
{
  const float* enc   = (const float*)d_in[0];
  const int*   msk   = (const int*)  d_in[1];
  const float* h1i   = (const float*)d_in[2];
  const float* c1i   = (const float*)d_in[3];
  const float* h2i   = (const float*)d_in[4];
  const float* c2i   = (const float*)d_in[5];
  const float* caps  = (const float*)d_in[6];
  const float* Wih1  = (const float*)d_in[7];
  const float* Whh1  = (const float*)d_in[8];
  const float* bih1  = (const float*)d_in[9];
  const float* bhh1  = (const float*)d_in[10];
  const float* Wih2  = (const float*)d_in[11];
  const float* Whh2  = (const float*)d_in[12];
  const float* bih2  = (const float*)d_in[13];
  const float* bhh2  = (const float*)d_in[14];
  const float* Watt  = (const float*)d_in[15];
  const float* batt  = (const float*)d_in[16];
  const float* Wcomb = (const float*)d_in[17];
  const float* bcomb = (const float*)d_in[18];
  float* out = (float*)d_out;

  char* p = (char*)d_ws;
  auto take = [&](size_t bytes){ char* r = p; p += (bytes + 255) & ~(size_t)255; return r; };
  float* pre1   = (float*)take((size_t)Tn * Bn * Gn * 4);          // 50.3 MB
  h16*   ench   = (h16*)take((size_t)Bn * Ln * HEn * 2);
  h16*   eph    = (h16*)take((size_t)Bn * Ln * Hn * 2);
  h16*   ecbh   = (h16*)take((size_t)Bn * Ln * Hn * 2);
  h16*   caph   = (h16*)take((size_t)Tn * Bn * En * 2);
  h16*   wih1h  = (h16*)take((size_t)Gn * En * 2);
  h16*   whh1h  = (h16*)take((size_t)Gn * Hn * 2);
  h16*   wih2h  = (h16*)take((size_t)Gn * 2 * Hn * 2);
  h16*   whh2h  = (h16*)take((size_t)Gn * Hn * 2);
  h16*   watth  = (h16*)take((size_t)Hn * HEn * 2);
  h16*   wcombh = (h16*)take((size_t)Hn * (HEn + Hn) * 2);
  h16*   h1b0   = (h16*)take((size_t)Bn * Hn * 2);
  h16*   h1b1   = (h16*)take((size_t)Bn * Hn * 2);
  h16*   h2b0   = (h16*)take((size_t)Bn * Hn * 2);
  h16*   h2b1   = (h16*)take((size_t)Bn * Hn * 2);
  h16*   oh     = (h16*)take((size_t)Bn * Hn * 2);
  float* c1     = (float*)take((size_t)Bn * Hn * 4);
  float* c2     = (float*)take((size_t)Bn * Hn * 4);
  float* h2f    = (float*)take((size_t)Bn * Hn * 4);
  float* ebuf   = (float*)take((size_t)Bn * Ln * 4);
  float* hwb    = (float*)take((size_t)Bn * Hn * 4);
  (void)ws_size; (void)n_in; (void)in_sizes; (void)out_size;

  CvtJobs jobs;
  jobs.src[0] = enc;   jobs.dst[0] = (h16x2*)ench;   jobs.n2[0] = Bn * Ln * HEn / 2;
  jobs.src[1] = caps;  jobs.dst[1] = (h16x2*)caph;   jobs.n2[1] = Tn * Bn * En / 2;
  jobs.src[2] = Wih1;  jobs.dst[2] = (h16x2*)wih1h;  jobs.n2[2] = Gn * En / 2;
  jobs.src[3] = Whh1;  jobs.dst[3] = (h16x2*)whh1h;  jobs.n2[3] = Gn * Hn / 2;
  jobs.src[4] = Wih2;  jobs.dst[4] = (h16x2*)wih2h;  jobs.n2[4] = Gn * 2 * Hn / 2;
  jobs.src[5] = Whh2;  jobs.dst[5] = (h16x2*)whh2h;  jobs.n2[5] = Gn * Hn / 2;
  jobs.src[6] = Watt;  jobs.dst[6] = (h16x2*)watth;  jobs.n2[6] = Hn * HEn / 2;
  jobs.src[7] = Wcomb; jobs.dst[7] = (h16x2*)wcombh; jobs.n2[7] = Hn * (HEn + Hn) / 2;
  cvt_all<<<2048, 256, 0, stream>>>(jobs);

  init_state<<<(Bn * Hn) / 256, 256, 0, stream>>>(h1i, c1i, h2i, c2i,
                                                  h1b0, c1, h2b0, c2, h2f, oh);

  // pre1 = captions @ Wih1^T + bih1 + bhh1   (3072 x 4096, K=512)
  gemm_lds<<<dim3((Tn * Bn) / 128, Gn / 128), 256, 0, stream>>>(
      caph, En, wih1h, En, bih1, bhh1, pre1, nullptr, Gn, En);
  // enc_proj = enc @ Watt^T + batt  (8192 x 1024, K=1024) -> fp16
  gemm_lds<<<dim3((Bn * Ln) / 128, Hn / 128), 256, 0, stream>>>(
      ench, HEn, watth, HEn, batt, nullptr, nullptr, eph, Hn, HEn);
  // enc_comb = enc @ Wcomb[:, :HE]^T  (8192 x 1024, K=1024) -> fp16
  gemm_lds<<<dim3((Bn * Ln) / 128, Hn / 128), 256, 0, stream>>>(
      ench, HEn, wcombh, HEn + Hn, nullptr, nullptr, nullptr, ecbh, Hn, HEn);

  // prime: gates1(0) -> h1(0) in h1b1 (h1 state for t lives in h1buf[(t+1)&1])
  kA<<<128, 512, 0, stream>>>(h1b0, h2b0, oh, h1b1, h2b1, h2f, c1, c2,
                              wih2h, whh2h, whh1h, bih2, bhh2, pre1, /*mode=*/0);

  h16* h1buf[2] = { h1b0, h1b1 };
  h16* h2buf[2] = { h2b0, h2b1 };
  for (int t = 0; t < Tn; t++){
    h16* h1cur  = h1buf[(t + 1) & 1];
    h16* h1next = h1buf[t & 1];
    h16* h2prev = h2buf[t & 1];
    h16* h2cur  = h2buf[(t + 1) & 1];
    const float* pre1_t = (t + 1 < Tn) ? (pre1 + (size_t)(t + 1) * Bn * Gn) : nullptr;
    kA<<<256, 512, 0, stream>>>(h1cur, h2prev, oh, h1next, h2cur, h2f, c1, c2,
                                wih2h, whh2h, whh1h, bih2, bhh2, pre1_t, /*mode=*/1);
    kB<<<2064, 256, 0, stream>>>(h2f, eph, msk, ebuf, h2cur, wcombh, bcomb, hwb);
    kC<<<256, 256, 0, stream>>>(t, ebuf, ecbh, hwb, out, oh);
  }
}